// Round 2
// baseline (24659.186 us; speedup 1.0000x reference)
//
#include <hip/hip_runtime.h>

typedef unsigned short u16;
using short8  = __attribute__((ext_vector_type(8))) short;
using floatx4 = __attribute__((ext_vector_type(4))) float;

#define BATCH 256
#define SEQ   256
#define INSZ  128
#define HID   1024
#define KDIM  1152   // INSZ + HID
#define NG    4096
#define ZS    1026
#define KPER  288    // KDIM / 4 splits
#define PARTSTRIDE (BATCH*NG)
#define NBLK  256

__device__ __forceinline__ u16 f2bf(float f) {
    union { float f; unsigned u; } v; v.f = f;
    unsigned r = v.u + 0x7fffu + ((v.u >> 16) & 1u);
    return (u16)(r >> 16);
}
__device__ __forceinline__ float sigf(float x)   { return 1.f / (1.f + __expf(-x)); }
__device__ __forceinline__ float tanhf_(float x) { return 1.f - 2.f / (__expf(2.f * x) + 1.f); }
__device__ __forceinline__ float wred(float v) {
#pragma unroll
    for (int o = 32; o > 0; o >>= 1) v += __shfl_down(v, o, 64);
    return v;
}

// device-scope grid barrier: cnt/gen pre-zeroed by hipMemsetAsync before launch.
// All 256 blocks are co-resident (1 block/CU). Agent-scope atomics + threadfence
// give cross-XCD visibility of the plain stores (per-XCD L2 non-coherence).
__device__ __forceinline__ void gsync(unsigned* cnt, unsigned* gen) {
    __syncthreads();
    if (threadIdx.x == 0) {
        __threadfence();  // release all prior plain stores, agent scope
        unsigned g = __hip_atomic_load(gen, __ATOMIC_RELAXED, __HIP_MEMORY_SCOPE_AGENT);
        unsigned arrived = __hip_atomic_fetch_add(cnt, 1u, __ATOMIC_ACQ_REL,
                                                  __HIP_MEMORY_SCOPE_AGENT);
        if (arrived == NBLK - 1) {
            __hip_atomic_store(cnt, 0u, __ATOMIC_RELAXED, __HIP_MEMORY_SCOPE_AGENT);
            __hip_atomic_fetch_add(gen, 1u, __ATOMIC_RELEASE, __HIP_MEMORY_SCOPE_AGENT);
        } else {
            while (__hip_atomic_load(gen, __ATOMIC_ACQUIRE, __HIP_MEMORY_SCOPE_AGENT) == g)
                __builtin_amdgcn_s_sleep(1);
        }
        __threadfence();  // acquire side for subsequent plain loads
    }
    __syncthreads();
}

__global__ void __launch_bounds__(256, 1) lstm_fused(
    const float* __restrict__ rnn, const float* __restrict__ tau,
    const float* __restrict__ z0,  const float* __restrict__ cz0,
    const float* __restrict__ WUw, const float* __restrict__ WUb,
    const float* __restrict__ aw,  const float* __restrict__ ab,
    const float* __restrict__ hw,  const float* __restrict__ hb,
    float* __restrict__ out,
    u16* __restrict__ Wbf, u16* __restrict__ Abuf, float* __restrict__ partial,
    float* __restrict__ cbuf, float* __restrict__ xbuf, float* __restrict__ wxbuf,
    unsigned* __restrict__ bar_cnt, unsigned* __restrict__ bar_gen)
{
    __shared__ __align__(16) u16 sA[128 * 32];
    __shared__ __align__(16) u16 sB[128 * 32];
    __shared__ float sred[4][4];

    const int tid  = threadIdx.x;
    const int bid  = blockIdx.x;
    const int gtid = bid * 256 + tid;

    // ---------------- setup: bf16 weight repack + state init ----------------
    for (int e = gtid; e < NG * KDIM; e += 65536) {
        int n = e / KDIM, k = e - n * KDIM;
        Wbf[e] = f2bf(WUw[n * 1154 + 2 + k]);
    }
    for (int e = gtid; e < NG * 2; e += 65536) {
        int n = e >> 1, s = e & 1;
        wxbuf[e] = WUw[n * 1154 + s];
    }
    for (int e = gtid; e < BATCH * KDIM; e += 65536) {
        int m = e / KDIM, k = e - m * KDIM;
        float v = (k < INSZ) ? rnn[m * SEQ * INSZ + k] : z0[m * ZS + 2 + (k - INSZ)];
        Abuf[e] = f2bf(v);
    }
    for (int e = gtid; e < BATCH * HID; e += 65536) {
        int m = e >> 10, j = e & 1023;
        cbuf[e] = cz0[m * ZS + 2 + j];
    }
    if (gtid < BATCH * 2) {
        int m = gtid >> 1, s = gtid & 1;
        xbuf[gtid] = z0[m * ZS + s];
    }
    gsync(bar_cnt, bar_gen);

    // ---------------- per-block GEMM decomposition ----------------
    const int ks   = bid & 3;          // K-split 0..3
    const int tile = bid >> 2;         // 0..63
    const int m0   = (tile & 1) * 128;
    const int n0   = (tile >> 1) * 128;
    const int lane = tid & 63, wid = tid >> 6;
    const int l15  = lane & 15, quad = lane >> 4;
    const int wm   = (wid & 1) * 64, wn = (wid >> 1) * 64;
    // staging: 2 x 16B pieces of A and B per thread per BK32 chunk
    const int r0 = tid >> 2,          c0 = (tid & 3) * 8;
    const int r1 = (tid + 256) >> 2,  c1 = ((tid + 256) & 3) * 8;
    const int kbase = ks * KPER;
    float* pp = partial + ks * PARTSTRIDE;

    for (int t = 0; t < SEQ; ++t) {
        // ================= GEMM: partial[ks] = A[:,kslice] * W[:,kslice]^T =================
        floatx4 zero4 = {0.f, 0.f, 0.f, 0.f};
        floatx4 acc[4][4];
#pragma unroll
        for (int a = 0; a < 4; ++a)
#pragma unroll
            for (int b = 0; b < 4; ++b) acc[a][b] = zero4;

        uint4 ra0, ra1, rb0, rb1;
#define LOADCHUNK(K0) do { \
        ra0 = *(const uint4*)(Abuf + (m0 + r0) * KDIM + (K0) + c0); \
        ra1 = *(const uint4*)(Abuf + (m0 + r1) * KDIM + (K0) + c1); \
        rb0 = *(const uint4*)(Wbf  + (n0 + r0) * KDIM + (K0) + c0); \
        rb1 = *(const uint4*)(Wbf  + (n0 + r1) * KDIM + (K0) + c1); \
    } while (0)

        LOADCHUNK(kbase);
        for (int c = 0; c < 9; ++c) {
            *(uint4*)&sA[r0 * 32 + c0] = ra0;
            *(uint4*)&sA[r1 * 32 + c1] = ra1;
            *(uint4*)&sB[r0 * 32 + c0] = rb0;
            *(uint4*)&sB[r1 * 32 + c1] = rb1;
            __syncthreads();
            if (c < 8) LOADCHUNK(kbase + (c + 1) * 32);
            short8 af[4], bf[4];
#pragma unroll
            for (int i = 0; i < 4; ++i)
                af[i] = *(const short8*)&sA[(wm + i * 16 + l15) * 32 + quad * 8];
#pragma unroll
            for (int i = 0; i < 4; ++i)
                bf[i] = *(const short8*)&sB[(wn + i * 16 + l15) * 32 + quad * 8];
#pragma unroll
            for (int mt = 0; mt < 4; ++mt)
#pragma unroll
                for (int nt = 0; nt < 4; ++nt)
                    acc[mt][nt] = __builtin_amdgcn_mfma_f32_16x16x32_bf16(
                        af[mt], bf[nt], acc[mt][nt], 0, 0, 0);
            __syncthreads();
        }
#undef LOADCHUNK
        // epilogue: write f32 partial tile (C/D layout: col=lane&15, row=quad*4+reg)
#pragma unroll
        for (int mt = 0; mt < 4; ++mt)
#pragma unroll
            for (int nt = 0; nt < 4; ++nt) {
                int row = m0 + wm + mt * 16 + quad * 4;
                int col = n0 + wn + nt * 16 + l15;
                float* dst = pp + row * NG + col;
#pragma unroll
                for (int i = 0; i < 4; ++i) dst[i * NG] = acc[mt][nt][i];
            }
        gsync(bar_cnt, bar_gen);

        // ================= pointwise: block = batch row =================
        {
            const int m = bid;
            float x0v = xbuf[m * 2 + 0], x1v = xbuf[m * 2 + 1];
            float sa0 = 0.f, sa1 = 0.f, sh0 = 0.f, sh1 = 0.f;
#pragma unroll
            for (int jj = 0; jj < 4; ++jj) {
                int j = jj * 256 + tid;
                float g4[4];
#pragma unroll
                for (int g = 0; g < 4; ++g) {
                    int n = g * 1024 + j;
                    float v = WUb[n] + x0v * wxbuf[2 * n] + x1v * wxbuf[2 * n + 1];
                    v += partial[0 * PARTSTRIDE + m * NG + n];
                    v += partial[1 * PARTSTRIDE + m * NG + n];
                    v += partial[2 * PARTSTRIDE + m * NG + n];
                    v += partial[3 * PARTSTRIDE + m * NG + n];
                    g4[g] = v;
                }
                float cg = cbuf[m * HID + j];
                float cn = sigf(g4[1]) * cg + sigf(g4[0]) * tanhf_(g4[2]);
                float hn = sigf(g4[3]) * tanhf_(cn);
                cbuf[m * HID + j] = cn;
                Abuf[m * KDIM + INSZ + j] = f2bf(hn);
                out[(m * SEQ + t) * ZS + 2 + j] = hn;
                sa0 += hn * aw[j];       sa1 += hn * aw[1024 + j];
                sh0 += hn * hw[j];       sh1 += hn * hw[1024 + j];
            }
            // stage u_{t+1} (bf16) for next step's GEMM
            if (t < SEQ - 1 && tid < INSZ)
                Abuf[m * KDIM + tid] = f2bf(rnn[(m * SEQ + t + 1) * INSZ + tid]);
            // block reduction of the 4 dot products
            sa0 = wred(sa0); sa1 = wred(sa1); sh0 = wred(sh0); sh1 = wred(sh1);
            if (lane == 0) { sred[0][wid] = sa0; sred[1][wid] = sa1; sred[2][wid] = sh0; sred[3][wid] = sh1; }
            __syncthreads();
            if (tid == 0) {
                float A0 = sred[0][0] + sred[0][1] + sred[0][2] + sred[0][3];
                float A1 = sred[1][0] + sred[1][1] + sred[1][2] + sred[1][3];
                float H0 = sred[2][0] + sred[2][1] + sred[2][2] + sred[2][3];
                float H1 = sred[3][0] + sred[3][1] + sred[3][2] + sred[3][3];
                float al0 = sigf(A0 + ab[0]);
                float al1 = sigf(A1 + ab[1]);
                float hx0 = H0 + hb[0];
                float hx1 = H1 + hb[1];
                float ta  = tau[m * SEQ + t];
                // M = I + tau*A, A = [[1.5,-1.5],[1/1.5,0]]
                float xm0 = (1.f + 1.5f * ta) * x0v - 1.5f * ta * x1v;
                float xm1 = (ta * (1.f / 1.5f)) * x0v + x1v;
                float xn0 = al0 * xm0 + (1.f - al0) * hx0;
                float xn1 = al1 * xm1 + (1.f - al1) * hx1;
                xbuf[m * 2 + 0] = xn0; xbuf[m * 2 + 1] = xn1;
                float* o = out + (m * SEQ + t) * ZS;
                o[0] = xn0; o[1] = xn1;
            }
        }
        gsync(bar_cnt, bar_gen);
    }

    // ---------------- final: z_f and cz_f ----------------
    {
        const int m = bid;
        float* zf  = out + (size_t)BATCH * SEQ * ZS;
        float* czf = zf + (size_t)BATCH * ZS;
        for (int i = tid; i < ZS; i += 256) {
            zf[m * ZS + i]  = out[(m * SEQ + (SEQ - 1)) * ZS + i];
            czf[m * ZS + i] = (i < 2) ? cz0[m * ZS + i] : cbuf[m * HID + i - 2];
        }
    }
}

extern "C" void kernel_launch(void* const* d_in, const int* in_sizes, int n_in,
                              void* d_out, int out_size, void* d_ws, size_t ws_size,
                              hipStream_t stream) {
    const float* rnn = (const float*)d_in[0];
    const float* tau = (const float*)d_in[1];
    const float* z0  = (const float*)d_in[2];
    const float* cz0 = (const float*)d_in[3];
    const float* WUw = (const float*)d_in[4];
    const float* WUb = (const float*)d_in[5];
    const float* aw  = (const float*)d_in[6];
    const float* ab  = (const float*)d_in[7];
    const float* hw  = (const float*)d_in[8];
    const float* hb  = (const float*)d_in[9];
    float* out = (float*)d_out;

    char* ws = (char*)d_ws;
    size_t off = 0;
    auto alloc = [&](size_t bytes) {
        void* p = ws + off;
        off += (bytes + 255) & ~(size_t)255;
        return p;
    };
    u16*   Wbf     = (u16*)  alloc((size_t)NG * KDIM * 2);     // 9.44 MB
    u16*   Abuf    = (u16*)  alloc((size_t)BATCH * KDIM * 2);  // 0.59 MB
    float* partial = (float*)alloc((size_t)4 * BATCH * NG * 4);// 16.8 MB
    float* cbuf    = (float*)alloc((size_t)BATCH * HID * 4);   // 1.05 MB
    float* xbuf    = (float*)alloc((size_t)BATCH * 2 * 4);
    float* wxbuf   = (float*)alloc((size_t)NG * 2 * 4);
    unsigned* bar_cnt = (unsigned*)alloc(256);                 // own cache line
    unsigned* bar_gen = (unsigned*)alloc(256);

    // barrier words must be zero before the kernel (ws is poisoned 0xAA).
    hipMemsetAsync(bar_cnt, 0, 256 * 2, stream);

    hipLaunchKernelGGL(lstm_fused, dim3(NBLK), dim3(256), 0, stream,
                       rnn, tau, z0, cz0, WUw, WUb, aw, ab, hw, hb,
                       out, Wbf, Abuf, partial, cbuf, xbuf, wxbuf,
                       bar_cnt, bar_gen);
}

// Round 3
// 9743.910 us; speedup vs baseline: 2.5307x; 2.5307x over previous
//
#include <hip/hip_runtime.h>

typedef unsigned short u16;
typedef unsigned int u32;
using short8  = __attribute__((ext_vector_type(8))) short;
using floatx4 = __attribute__((ext_vector_type(4))) float;

#define BATCH 256
#define SEQ   256
#define INSZ  128
#define HID   1024
#define KDIM  1152
#define ZS    1026
#define NBLK  256
#define MT    64      // rows per block
#define BK    128     // k-chunk
#define NCH   9       // 1152/128
#define SASTR 136     // sA row stride (bf16) padded
#define SCSTR 68      // sC row stride (f32) padded

#define AL_RLX __ATOMIC_RELAXED
#define AL_REL __ATOMIC_RELEASE
#define SC_AGT __HIP_MEMORY_SCOPE_AGENT

__device__ __forceinline__ u16 f2bf(float f) {
    union { float f; unsigned u; } v; v.f = f;
    unsigned r = v.u + 0x7fffu + ((v.u >> 16) & 1u);
    return (u16)(r >> 16);
}
__device__ __forceinline__ u32 pack2(float a, float b) {
    return (u32)f2bf(a) | ((u32)f2bf(b) << 16);
}
__device__ __forceinline__ float sigf(float x)   { return 1.f / (1.f + __expf(-x)); }
__device__ __forceinline__ float tanhf_(float x) { return 1.f - 2.f / (__expf(2.f * x) + 1.f); }

// coherent (L2-bypass) dword ops — the ONLY way Abuf/D are touched after setup
__device__ __forceinline__ u32 cload(const u32* p) {
    return __hip_atomic_load(p, AL_RLX, SC_AGT);
}
__device__ __forceinline__ void cstore(u32* p, u32 v) {
    __hip_atomic_store(p, v, AL_RLX, SC_AGT);
}

__global__ void __launch_bounds__(256, 1) lstm_fused(
    const float* __restrict__ rnn, const float* __restrict__ tau,
    const float* __restrict__ z0,  const float* __restrict__ cz0,
    const float* __restrict__ WUw, const float* __restrict__ WUb,
    const float* __restrict__ aw,  const float* __restrict__ ab,
    const float* __restrict__ hw,  const float* __restrict__ hb,
    float* __restrict__ out,
    u16* __restrict__ Wp, u32* __restrict__ Abuf32, float* __restrict__ D,
    float* __restrict__ bp, float* __restrict__ wxp,
    unsigned* __restrict__ bar_cnt, unsigned* __restrict__ bar_gen)
{
    __shared__ __align__(16) char lds[2 * MT * SASTR * 2];   // sA | sB (34,816 B)
    __shared__ float sX[128];

    u16* sA = (u16*)lds;
    u16* sB = (u16*)(lds + MT * SASTR * 2);
    float* sC = (float*)lds;                   // reuse sA region after GEMM
    float* sH = (float*)(lds + MT * SASTR * 2); // reuse sB region in pointwise

    const int tid = threadIdx.x;
    const int bid = blockIdx.x;
    const int gtid = bid * 256 + tid;

    // block decomposition: xcd-partitioned W locality
    const int xcd = bid & 7, q = (bid >> 3) & 7, mt = bid >> 6;
    const int jt = xcd * 8 + q;          // 0..63 (16 j's each)
    const int m0 = mt * 64;
    const int j0 = jt * 16;
    const bool writer = ((bid & 63) == 0);   // jt==0: one per mtile

    const int lane = tid & 63, wid = tid >> 6;
    const int l15 = lane & 15, quad = lane >> 4;
    const int wm = (wid & 1) * 32, wn = (wid >> 1) * 32;

    // ---------------- setup ----------------
    // W repack: Wp[jt][r][k], r = g*16+jj <-> n = g*1024 + jt*16 + jj
    {
        const int jts = bid >> 2, q4 = bid & 3;
        for (int r = q4 * 16; r < q4 * 16 + 16; ++r) {
            int n = (r >> 4) * 1024 + jts * 16 + (r & 15);
            const float* src = WUw + (size_t)n * 1154 + 2;
            u16* dst = Wp + (size_t)jts * 73728 + r * 1152;
            for (int k = tid; k < 1152; k += 256) dst[k] = f2bf(src[k]);
        }
    }
    // bias / x-weight repack (r-order)
    if (gtid < 4096) {
        int jte = gtid >> 6, r = gtid & 63;
        int n = (r >> 4) * 1024 + jte * 16 + (r & 15);
        bp[gtid] = WUb[n];
        wxp[2 * gtid] = WUw[(size_t)n * 1154];
        wxp[2 * gtid + 1] = WUw[(size_t)n * 1154 + 1];
    }
    // Abuf init: row = bid, dword col c: [u_t=0 (64 dw) | h0 (512 dw)]
    {
        int m = bid;
        for (int c = tid; c < 576; c += 256) {
            int k = 2 * c;
            float v0, v1;
            if (k < 128) { v0 = rnn[(size_t)m * SEQ * INSZ + k]; v1 = rnn[(size_t)m * SEQ * INSZ + k + 1]; }
            else { v0 = z0[m * ZS + 2 + (k - 128)]; v1 = z0[m * ZS + 2 + (k - 127)]; }
            Abuf32[m * 576 + c] = pack2(v0, v1);   // plain; flushed by setup fence
        }
    }
    if (gtid < 3072) D[gtid] = 0.f;

    // c-state in registers for the whole sequence: cell i -> (m=(tid>>4)+16i, jj=tid&15)
    float cr[4];
#pragma unroll
    for (int i = 0; i < 4; ++i) {
        int m = (tid >> 4) + 16 * i, jj = tid & 15;
        cr[i] = cz0[(m0 + m) * ZS + 2 + j0 + jj];
    }
    // x-state (threads 0..63 hold row m0+tid)
    float xp0 = 0.f, xp1 = 0.f;
    if (tid < 64) { xp0 = z0[(m0 + tid) * ZS + 0]; xp1 = z0[(m0 + tid) * ZS + 1]; }

    // setup barrier WITH full fences (flush plain-written Wp/Abuf/bp to coherence point)
    __syncthreads();
    if (tid == 0) {
        __threadfence();
        unsigned g = __hip_atomic_load(bar_gen, AL_RLX, SC_AGT);
        unsigned a = __hip_atomic_fetch_add(bar_cnt, 1u, __ATOMIC_ACQ_REL, SC_AGT);
        if (a == NBLK - 1) {
            __hip_atomic_store(bar_cnt, 0u, AL_RLX, SC_AGT);
            __hip_atomic_fetch_add(bar_gen, 1u, AL_REL, SC_AGT);
        } else {
            while (__hip_atomic_load(bar_gen, __ATOMIC_ACQUIRE, SC_AGT) == g)
                __builtin_amdgcn_s_sleep(2);
        }
        __threadfence();
    }
    __syncthreads();

    const u16* WpT = Wp + (size_t)jt * 73728;
    float* zf  = out + (size_t)BATCH * SEQ * ZS;
    float* czf = zf + (size_t)BATCH * ZS;

    for (int t = 0; t < SEQ; ++t) {
        // ---------- phase X: x-state for this step (block-local, replicated) ----------
        if (tid < 64) {
            int mg = m0 + tid;
            if (t == 0) {
                sX[tid * 2] = xp0; sX[tid * 2 + 1] = xp1;
            } else {
                const float* Dp = D + ((t - 1) % 3) * 1024 + mg * 4;
                float s0 = __hip_atomic_load(Dp + 0, AL_RLX, SC_AGT);
                float s1 = __hip_atomic_load(Dp + 1, AL_RLX, SC_AGT);
                float s2 = __hip_atomic_load(Dp + 2, AL_RLX, SC_AGT);
                float s3 = __hip_atomic_load(Dp + 3, AL_RLX, SC_AGT);
                float al0 = sigf(s0 + ab[0]), al1 = sigf(s1 + ab[1]);
                float hx0 = s2 + hb[0], hx1 = s3 + hb[1];
                float ta = tau[mg * SEQ + (t - 1)];
                float xm0 = (1.f + 1.5f * ta) * xp0 - 1.5f * ta * xp1;
                float xm1 = (ta * (1.f / 1.5f)) * xp0 + xp1;
                float xn0 = al0 * xm0 + (1.f - al0) * hx0;
                float xn1 = al1 * xm1 + (1.f - al1) * hx1;
                xp0 = xn0; xp1 = xn1;
                sX[tid * 2] = xn0; sX[tid * 2 + 1] = xn1;
                if (writer) {
                    float* o = out + ((size_t)mg * SEQ + (t - 1)) * ZS;
                    o[0] = xn0; o[1] = xn1;
                }
            }
        }
        // writer blocks zero D[(t+1)%3] (reused 2 steps from now)
        if (writer) {
            float* Dz = D + ((t + 1) % 3) * 1024 + m0 * 4;
            __hip_atomic_store(Dz + tid, 0.f, AL_RLX, SC_AGT);
        }
        __syncthreads();

        // ---------- GEMM: C(64x64) = A(64x1152) * Wp_tile(64x1152)^T ----------
        floatx4 acc[2][2];
        floatx4 z4 = {0.f, 0.f, 0.f, 0.f};
        acc[0][0] = z4; acc[0][1] = z4; acc[1][0] = z4; acc[1][1] = z4;

        u32  aR[16];
        uint4 wR[4];
#define LOADA(CH) do { _Pragma("unroll") \
        for (int i = 0; i < 16; ++i) { int d = tid + i * 256; \
            aR[i] = cload(Abuf32 + (m0 + (d >> 6)) * 576 + (CH) * 64 + (d & 63)); } } while (0)
#define LOADW(CH) do { _Pragma("unroll") \
        for (int i = 0; i < 4; ++i) { int s = tid + i * 256; \
            wR[i] = *(const uint4*)(WpT + (size_t)(s >> 4) * 1152 + (CH) * 128 + (s & 15) * 8); } } while (0)

        LOADA(0); LOADW(0);
        for (int ch = 0; ch < NCH; ++ch) {
#pragma unroll
            for (int i = 0; i < 16; ++i) { int d = tid + i * 256;
                *(u32*)&sA[(d >> 6) * SASTR + (d & 63) * 2] = aR[i]; }
#pragma unroll
            for (int i = 0; i < 4; ++i) { int s = tid + i * 256;
                *(uint4*)&sB[(s >> 4) * SASTR + (s & 15) * 8] = wR[i]; }
            __syncthreads();
            if (ch < NCH - 1) { LOADA(ch + 1); LOADW(ch + 1); }
#pragma unroll
            for (int kk = 0; kk < 4; ++kk) {
                short8 af[2], bf[2];
#pragma unroll
                for (int i = 0; i < 2; ++i)
                    af[i] = *(const short8*)&sA[(wm + i * 16 + l15) * SASTR + kk * 32 + quad * 8];
#pragma unroll
                for (int i = 0; i < 2; ++i)
                    bf[i] = *(const short8*)&sB[(wn + i * 16 + l15) * SASTR + kk * 32 + quad * 8];
#pragma unroll
                for (int i = 0; i < 2; ++i)
#pragma unroll
                    for (int j = 0; j < 2; ++j)
                        acc[i][j] = __builtin_amdgcn_mfma_f32_16x16x32_bf16(af[i], bf[j], acc[i][j], 0, 0, 0);
            }
            __syncthreads();
        }
#undef LOADA
#undef LOADW

        // ---------- exchange C through LDS (gates split across waves) ----------
#pragma unroll
        for (int i = 0; i < 2; ++i)
#pragma unroll
            for (int j = 0; j < 2; ++j) {
                int row = wm + i * 16 + quad * 4, col = wn + j * 16 + l15;
#pragma unroll
                for (int rr = 0; rr < 4; ++rr)
                    sC[(row + rr) * SCSTR + col] = acc[i][j][rr];
            }
        __syncthreads();

        // ---------- pointwise: cell i -> (m=(tid>>4)+16i, jj=tid&15) ----------
        float hv[4];
        float p0 = 0.f, p1 = 0.f, p2 = 0.f, p3 = 0.f;
        {
            float sx0, sx1;
#pragma unroll
            for (int i = 0; i < 4; ++i) {
                int m = (tid >> 4) + 16 * i, jj = tid & 15;
                int r = jj;  // base row in tile; gates at r, 16+r, 32+r, 48+r
                sx0 = sX[m * 2]; sx1 = sX[m * 2 + 1];
                float gi = bp[jt * 64 + 0 * 16 + jj] + wxp[(jt * 64 + 0 * 16 + jj) * 2] * sx0 + wxp[(jt * 64 + 0 * 16 + jj) * 2 + 1] * sx1 + sC[m * SCSTR + 0 * 16 + jj];
                float gf = bp[jt * 64 + 1 * 16 + jj] + wxp[(jt * 64 + 1 * 16 + jj) * 2] * sx0 + wxp[(jt * 64 + 1 * 16 + jj) * 2 + 1] * sx1 + sC[m * SCSTR + 1 * 16 + jj];
                float gg = bp[jt * 64 + 2 * 16 + jj] + wxp[(jt * 64 + 2 * 16 + jj) * 2] * sx0 + wxp[(jt * 64 + 2 * 16 + jj) * 2 + 1] * sx1 + sC[m * SCSTR + 2 * 16 + jj];
                float go = bp[jt * 64 + 3 * 16 + jj] + wxp[(jt * 64 + 3 * 16 + jj) * 2] * sx0 + wxp[(jt * 64 + 3 * 16 + jj) * 2 + 1] * sx1 + sC[m * SCSTR + 3 * 16 + jj];
                float cn = sigf(gf) * cr[i] + sigf(gi) * tanhf_(gg);
                float hn = sigf(go) * tanhf_(cn);
                cr[i] = cn;
                hv[i] = hn;
                int jgl = j0 + jj, mg = m0 + m;
                out[((size_t)mg * SEQ + t) * ZS + 2 + jgl] = hn;
                if (t == SEQ - 1) { zf[mg * ZS + 2 + jgl] = hn; czf[mg * ZS + 2 + jgl] = cn; }
                p0 = hn * aw[jgl];        p1 = hn * aw[1024 + jgl];
                p2 = hn * hw[jgl];        p3 = hn * hw[1024 + jgl];
                // reduce over the 16 jj-lanes (contiguous within wave)
#pragma unroll
                for (int o = 8; o > 0; o >>= 1) {
                    p0 += __shfl_down(p0, o, 16); p1 += __shfl_down(p1, o, 16);
                    p2 += __shfl_down(p2, o, 16); p3 += __shfl_down(p3, o, 16);
                }
                if ((tid & 15) == 0) {
                    float* Dp = D + (t % 3) * 1024 + mg * 4;
                    __hip_atomic_fetch_add(Dp + 0, p0, AL_RLX, SC_AGT);
                    __hip_atomic_fetch_add(Dp + 1, p1, AL_RLX, SC_AGT);
                    __hip_atomic_fetch_add(Dp + 2, p2, AL_RLX, SC_AGT);
                    __hip_atomic_fetch_add(Dp + 3, p3, AL_RLX, SC_AGT);
                }
                (void)r;
            }
        }
        // h -> Abuf (bf16, coherent): exchange pairs through sH[jj*65+m]
#pragma unroll
        for (int i = 0; i < 4; ++i) {
            int m = (tid >> 4) + 16 * i, jj = tid & 15;
            sH[jj * 65 + m] = hv[i];
        }
        __syncthreads();
#pragma unroll
        for (int i = 0; i < 2; ++i) {
            int dd = tid + i * 256;
            int m = dd >> 3, jp = dd & 7;
            u32 v = pack2(sH[(2 * jp) * 65 + m], sH[(2 * jp + 1) * 65 + m]);
            cstore(Abuf32 + (m0 + m) * 576 + 64 + jt * 8 + jp, v);
        }
        // u_{t+1} staging (writer blocks)
        if (writer && t < SEQ - 1) {
#pragma unroll
            for (int i = 0; i < 16; ++i) {
                int d = tid + i * 256;
                int row = d >> 6, dc = d & 63, mg = m0 + row;
                float2 uv = *(const float2*)(rnn + ((size_t)mg * SEQ + t + 1) * INSZ + 2 * dc);
                cstore(Abuf32 + mg * 576 + dc, pack2(uv.x, uv.y));
            }
        }

        // ---------- lean grid barrier (release on arrive; no acquire needed:
        // all cross-step reads are coherent/bypass ops) ----------
        __syncthreads();
        if (tid == 0) {
            unsigned g = __hip_atomic_load(bar_gen, AL_RLX, SC_AGT);
            unsigned a = __hip_atomic_fetch_add(bar_cnt, 1u, AL_REL, SC_AGT);
            if (a == NBLK - 1) {
                __hip_atomic_store(bar_cnt, 0u, AL_RLX, SC_AGT);
                __hip_atomic_fetch_add(bar_gen, 1u, AL_REL, SC_AGT);
            } else {
                while (__hip_atomic_load(bar_gen, AL_RLX, SC_AGT) == g)
                    __builtin_amdgcn_s_sleep(2);
            }
        }
        __syncthreads();
    }

    // ---------- final x-update (t = SEQ) + frozen cz columns ----------
    if (tid < 64) {
        int mg = m0 + tid;
        const float* Dp = D + ((SEQ - 1) % 3) * 1024 + mg * 4;
        float s0 = __hip_atomic_load(Dp + 0, AL_RLX, SC_AGT);
        float s1 = __hip_atomic_load(Dp + 1, AL_RLX, SC_AGT);
        float s2 = __hip_atomic_load(Dp + 2, AL_RLX, SC_AGT);
        float s3 = __hip_atomic_load(Dp + 3, AL_RLX, SC_AGT);
        float al0 = sigf(s0 + ab[0]), al1 = sigf(s1 + ab[1]);
        float hx0 = s2 + hb[0], hx1 = s3 + hb[1];
        float ta = tau[mg * SEQ + (SEQ - 1)];
        float xm0 = (1.f + 1.5f * ta) * xp0 - 1.5f * ta * xp1;
        float xm1 = (ta * (1.f / 1.5f)) * xp0 + xp1;
        float xn0 = al0 * xm0 + (1.f - al0) * hx0;
        float xn1 = al1 * xm1 + (1.f - al1) * hx1;
        if (writer) {
            float* o = out + ((size_t)mg * SEQ + (SEQ - 1)) * ZS;
            o[0] = xn0; o[1] = xn1;
            zf[mg * ZS + 0] = xn0; zf[mg * ZS + 1] = xn1;
            czf[mg * ZS + 0] = cz0[mg * ZS + 0];
            czf[mg * ZS + 1] = cz0[mg * ZS + 1];
        }
    }
}

extern "C" void kernel_launch(void* const* d_in, const int* in_sizes, int n_in,
                              void* d_out, int out_size, void* d_ws, size_t ws_size,
                              hipStream_t stream) {
    const float* rnn = (const float*)d_in[0];
    const float* tau = (const float*)d_in[1];
    const float* z0  = (const float*)d_in[2];
    const float* cz0 = (const float*)d_in[3];
    const float* WUw = (const float*)d_in[4];
    const float* WUb = (const float*)d_in[5];
    const float* aw  = (const float*)d_in[6];
    const float* ab  = (const float*)d_in[7];
    const float* hw  = (const float*)d_in[8];
    const float* hb  = (const float*)d_in[9];
    float* out = (float*)d_out;

    char* ws = (char*)d_ws;
    size_t off = 0;
    auto alloc = [&](size_t bytes) {
        void* p = ws + off;
        off += (bytes + 255) & ~(size_t)255;
        return p;
    };
    u16*   Wp     = (u16*)alloc((size_t)64 * 64 * 1152 * 2);   // 9.44 MB, jt-major
    u32*   Abuf32 = (u32*)alloc((size_t)BATCH * 576 * 4);      // 0.59 MB
    float* D      = (float*)alloc((size_t)3 * BATCH * 4 * 4);  // 12 KB
    float* bp     = (float*)alloc((size_t)4096 * 4);
    float* wxp    = (float*)alloc((size_t)8192 * 4);
    unsigned* bar_cnt = (unsigned*)alloc(256);
    unsigned* bar_gen = (unsigned*)alloc(256);

    hipMemsetAsync(bar_cnt, 0, 512, stream);

    hipLaunchKernelGGL(lstm_fused, dim3(NBLK), dim3(256), 0, stream,
                       rnn, tau, z0, cz0, WUw, WUb, aw, ab, hw, hb,
                       out, Wp, Abuf32, D, bp, wxp, bar_cnt, bar_gen);
}